// Round 7
// baseline (259.957 us; speedup 1.0000x reference)
//
#include <hip/hip_runtime.h>

#define N_NODES 50000
#define N_EDGES 1600000
#define D 48

#define EPB 32768           // edges per count/fill block (long runs -> full-line fills)
#define PB  49              // ceil(N_EDGES/EPB)
#define NPB_D 64
#define NBIN_D 782          // ceil(50000/64)
#define NPB_S 256
#define NBIN_S 196          // ceil(50000/256)

// ---------- workspace layout (bytes) ----------
#define RECD_OFF  0          // u32[1.6M] dst-binned packed (src<<6)|dlocal; becomes col[] after k_csr (16B aligned)
#define SRCB_OFF  6400000    // u8 [1.6M] src-binned (src & 255)
#define CI_OFF    8000000    // f32[50000]
#define CNTD_OFF  8200000    // int[PB][NBIN_D]
#define CNTS_OFF  8353280    // int[PB][NBIN_S]
#define OFFD_OFF  8391696    // int[NBIN_D][PB]
#define OFFS_OFF  8544968    // int[NBIN_S][PB]
#define TOTD_OFF  8583384    // int[NBIN_D]
#define TOTS_OFF  8586512    // int[NBIN_S]
#define BPD_OFF   8587296    // int[NBIN_D+1]
#define BPS_OFF   8590432    // int[NBIN_S+1]
#define RPTR_OFF  8591232    // int[50001]
#define SFEAT_OFF 8791296    // f32[50000*48] prescaled features (optional)
#define SFEAT_END 18391296

__global__ __launch_bounds__(1024) void k_count(const int* __restrict__ src,
                                                const int* __restrict__ dst,
                                                int* __restrict__ cntd,
                                                int* __restrict__ cnts) {
    __shared__ int cd[NBIN_D];
    __shared__ int cs[NBIN_S];
    int tid = threadIdx.x;
    for (int i = tid; i < NBIN_D; i += 1024) cd[i] = 0;
    for (int i = tid; i < NBIN_S; i += 1024) cs[i] = 0;
    __syncthreads();
    int base = blockIdx.x * EPB;
    int end = min(base + EPB, N_EDGES);
    for (int e = base + tid; e < end; e += 1024) {
        atomicAdd(&cd[dst[e] >> 6], 1);
        atomicAdd(&cs[src[e] >> 8], 1);
    }
    __syncthreads();
    for (int i = tid; i < NBIN_D; i += 1024) cntd[blockIdx.x * NBIN_D + i] = cd[i];
    for (int i = tid; i < NBIN_S; i += 1024) cnts[blockIdx.x * NBIN_S + i] = cs[i];
}

// one block per bin: exclusive scan of per-block counts (over PB blocks)
__global__ __launch_bounds__(256) void k_binscan(const int* __restrict__ cntT, int nbin,
                                                 int* __restrict__ off, int* __restrict__ tot) {
    __shared__ int ts[256];
    int t = threadIdx.x, bin = blockIdx.x;
    int v = (t < PB) ? cntT[t * nbin + bin] : 0;
    ts[t] = v;
    __syncthreads();
    for (int o = 1; o < 256; o <<= 1) {
        int x = (t >= o) ? ts[t - o] : 0;
        __syncthreads();
        ts[t] += x;
        __syncthreads();
    }
    int incl = ts[t];
    if (t < PB) off[bin * PB + t] = incl - v;
    if (t == 255) tot[bin] = incl;
}

// single block: exclusive scan of n<=1024 bin totals -> bin_ptr[0..n]
__global__ __launch_bounds__(256) void k_scan_small(const int* __restrict__ in, int n,
                                                    int* __restrict__ out) {
    __shared__ int ts[256];
    int t = threadIdx.x;
    int base = t * 4;
    int a0 = (base + 0 < n) ? in[base + 0] : 0;
    int a1 = (base + 1 < n) ? in[base + 1] : 0;
    int a2 = (base + 2 < n) ? in[base + 2] : 0;
    int a3 = (base + 3 < n) ? in[base + 3] : 0;
    int tot4 = a0 + a1 + a2 + a3;
    ts[t] = tot4;
    __syncthreads();
    for (int o = 1; o < 256; o <<= 1) {
        int x = (t >= o) ? ts[t - o] : 0;
        __syncthreads();
        ts[t] += x;
        __syncthreads();
    }
    int excl = ts[t] - tot4;
    if (base + 0 < n) out[base + 0] = excl;
    if (base + 1 < n) out[base + 1] = excl + a0;
    if (base + 2 < n) out[base + 2] = excl + a0 + a1;
    if (base + 3 < n) out[base + 3] = excl + a0 + a1 + a2;
    if (t == 255) out[n] = ts[255];
}

__global__ __launch_bounds__(1024) void k_fill(const int* __restrict__ src,
                                               const int* __restrict__ dst,
                                               const int* __restrict__ offd,
                                               const int* __restrict__ offs,
                                               const int* __restrict__ bpd,
                                               const int* __restrict__ bps,
                                               unsigned int* __restrict__ rec,
                                               unsigned char* __restrict__ srcb) {
    __shared__ int curd[NBIN_D];
    __shared__ int curs[NBIN_S];
    int tid = threadIdx.x, blk = blockIdx.x;
    for (int i = tid; i < NBIN_D; i += 1024) curd[i] = bpd[i] + offd[i * PB + blk];
    for (int i = tid; i < NBIN_S; i += 1024) curs[i] = bps[i] + offs[i * PB + blk];
    __syncthreads();
    int base = blk * EPB;
    int end = min(base + EPB, N_EDGES);
    for (int e = base + tid; e < end; e += 1024) {
        int s = src[e], d = dst[e];
        int pd = atomicAdd(&curd[d >> 6], 1);
        rec[pd] = ((unsigned int)s << 6) | (unsigned int)(d & 63);
        int ps = atomicAdd(&curs[s >> 8], 1);
        srcb[ps] = (unsigned char)s;
    }
}

// one block per src-bin: LDS out-degree histogram -> ci (+ optional sfeat = feat*ci)
__global__ __launch_bounds__(256) void k_ci(const unsigned char* __restrict__ srcb,
                                            const int* __restrict__ bps,
                                            const float* __restrict__ feat,
                                            float* __restrict__ ci,
                                            float* __restrict__ sfeat,
                                            int do_scale) {
    __shared__ int cnt[NPB_S];
    __shared__ float cl[NPB_S];
    int t = threadIdx.x, bin = blockIdx.x;
    cnt[t] = 0;
    __syncthreads();
    int beg = bps[bin], end = bps[bin + 1];
    for (int j = beg + t; j < end; j += 256)
        atomicAdd(&cnt[srcb[j]], 1);
    __syncthreads();
    float c = rsqrtf(fmaxf((float)cnt[t], 1.0f));
    cl[t] = c;
    int n = bin * NPB_S + t;
    if (n < N_NODES) ci[n] = c;
    __syncthreads();
    if (do_scale) {
        size_t nb = (size_t)bin * NPB_S * D;
        int lim = min(NPB_S * D, (N_NODES - bin * NPB_S) * D);
        for (int i = t; i < lim; i += 256)
            sfeat[nb + i] = feat[nb + i] * cl[i / D];
    }
}

// one block per dst-bin: stage bin edges in LDS, count+scan in-degrees ->
// rowptr, then reorder in place (rec -> per-node-grouped col of src ids).
__global__ __launch_bounds__(256) void k_csr(unsigned int* __restrict__ rec,
                                             const int* __restrict__ bpd,
                                             int* __restrict__ rowptr) {
    __shared__ unsigned int ebuf[3072];   // bin edge count ~2048, sigma ~45
    __shared__ int ideg[NPB_D];
    __shared__ int off[NPB_D];
    __shared__ int cur[NPB_D];
    int tid = threadIdx.x, bin = blockIdx.x;
    int beg = bpd[bin], end = bpd[bin + 1];
    int cnt = end - beg;
    if (cnt > 3072) cnt = 3072;           // unreachable; guards LDS OOB
    if (tid < NPB_D) { ideg[tid] = 0; cur[tid] = 0; }
    __syncthreads();
    for (int j = tid; j < cnt; j += 256) {
        unsigned int r = rec[beg + j];
        ebuf[j] = r;
        atomicAdd(&ideg[r & 63], 1);
    }
    __syncthreads();
    if (tid < NPB_D) {
        int v = ideg[tid];
        int incl = v;
        for (int o = 1; o < 64; o <<= 1) {
            int u = __shfl_up(incl, o);
            if (tid >= o) incl += u;
        }
        int ex = incl - v;
        off[tid] = ex;
        int n = bin * NPB_D + tid;
        if (n < N_NODES) rowptr[n] = beg + ex;
    }
    if (bin == NBIN_D - 1 && tid == 0) rowptr[N_NODES] = N_EDGES;
    __syncthreads();
    for (int j = tid; j < cnt; j += 256) {
        unsigned int r = ebuf[j];
        int dl = r & 63;
        int p = atomicAdd(&cur[dl], 1);
        rec[beg + off[dl] + p] = r >> 6;   // now plain src id
    }
}

// one wave per dst node: register-accumulating gather, fused GEMM + ReLU
template <bool PRESCALED>
__global__ __launch_bounds__(256) void k_gcn(
    const int* __restrict__ rowptr, const int* __restrict__ col,
    const float* __restrict__ ci, const float* __restrict__ sfeat,
    const float* __restrict__ feat,
    const float* __restrict__ W, const float* __restrict__ b,
    float* __restrict__ out) {
    __shared__ float Wl[D * 49];
    __shared__ float bl[D];
    __shared__ float hl[4 * 49];
    int tid = threadIdx.x;

    for (int i = tid; i < D * D; i += 256) {
        int od = i / D, k = i - od * D;
        Wl[od * 49 + k] = W[i];
    }
    if (tid < D) bl[tid] = b[tid];

    int wave = tid >> 6;
    int lane = tid & 63;
    int n = blockIdx.x * 4 + wave;
    int kk = (lane < D) ? lane : 0;

    int beg = 0, end = 0;
    if (n < N_NODES) { beg = rowptr[n]; end = rowptr[n + 1]; }

    float acc0 = 0.0f, acc1 = 0.0f;
    int j = beg;
    // peel to 16B alignment of col+j (col base is 16B aligned)
    int pre = (4 - (j & 3)) & 3;
    if (pre > end - j) pre = end - j;
    for (int t = 0; t < pre; ++t, ++j) {
        int s = col[j];
        if (PRESCALED) acc0 += sfeat[(size_t)s * D + kk];
        else           acc0 += feat[(size_t)s * D + kk] * ci[s];
    }
    for (; j + 8 <= end; j += 8) {
        int4 a = *(const int4*)(col + j);
        int4 c4 = *(const int4*)(col + j + 4);
        if (PRESCALED) {
            acc0 += sfeat[(size_t)a.x * D + kk];
            acc1 += sfeat[(size_t)a.y * D + kk];
            acc0 += sfeat[(size_t)a.z * D + kk];
            acc1 += sfeat[(size_t)a.w * D + kk];
            acc0 += sfeat[(size_t)c4.x * D + kk];
            acc1 += sfeat[(size_t)c4.y * D + kk];
            acc0 += sfeat[(size_t)c4.z * D + kk];
            acc1 += sfeat[(size_t)c4.w * D + kk];
        } else {
            acc0 += feat[(size_t)a.x * D + kk] * ci[a.x];
            acc1 += feat[(size_t)a.y * D + kk] * ci[a.y];
            acc0 += feat[(size_t)a.z * D + kk] * ci[a.z];
            acc1 += feat[(size_t)a.w * D + kk] * ci[a.w];
            acc0 += feat[(size_t)c4.x * D + kk] * ci[c4.x];
            acc1 += feat[(size_t)c4.y * D + kk] * ci[c4.y];
            acc0 += feat[(size_t)c4.z * D + kk] * ci[c4.z];
            acc1 += feat[(size_t)c4.w * D + kk] * ci[c4.w];
        }
    }
    for (; j < end; ++j) {
        int s = col[j];
        if (PRESCALED) acc0 += sfeat[(size_t)s * D + kk];
        else           acc0 += feat[(size_t)s * D + kk] * ci[s];
    }
    float acc = acc0 + acc1;

    float res = 0.0f;
    if (n < N_NODES) {
        int indeg = end - beg;
        res = (indeg > 0) ? acc * rsqrtf((float)indeg)
                          : feat[(size_t)n * D + kk];
    }
    if (lane < D) hl[wave * 49 + lane] = res;
    __syncthreads();

    if (tid < 4 * D) {
        int nl = tid / D, od = tid - nl * D;
        int n2 = blockIdx.x * 4 + nl;
        if (n2 < N_NODES) {
            float a2 = bl[od];
            #pragma unroll
            for (int k = 0; k < D; k++)
                a2 = fmaf(hl[nl * 49 + k], Wl[od * 49 + k], a2);
            out[(size_t)n2 * D + od] = fmaxf(a2, 0.0f);
        }
    }
}

extern "C" void kernel_launch(void* const* d_in, const int* in_sizes, int n_in,
                              void* d_out, int out_size, void* d_ws, size_t ws_size,
                              hipStream_t stream) {
    const float* feat = (const float*)d_in[0];
    const int*   src  = (const int*)d_in[1];
    const int*   dst  = (const int*)d_in[2];
    const float* W    = (const float*)d_in[3];
    const float* b    = (const float*)d_in[4];
    float* out = (float*)d_out;

    char* ws = (char*)d_ws;
    unsigned int*  rec  = (unsigned int*)(ws + RECD_OFF);
    unsigned char* srcb = (unsigned char*)(ws + SRCB_OFF);
    float* ci    = (float*)(ws + CI_OFF);
    int*   cntd  = (int*)(ws + CNTD_OFF);
    int*   cnts  = (int*)(ws + CNTS_OFF);
    int*   offd  = (int*)(ws + OFFD_OFF);
    int*   offs  = (int*)(ws + OFFS_OFF);
    int*   totd  = (int*)(ws + TOTD_OFF);
    int*   tots  = (int*)(ws + TOTS_OFF);
    int*   bpd   = (int*)(ws + BPD_OFF);
    int*   bps   = (int*)(ws + BPS_OFF);
    int*   rptr  = (int*)(ws + RPTR_OFF);
    float* sfeat = (float*)(ws + SFEAT_OFF);

    const bool prescale = (ws_size >= (size_t)SFEAT_END);

    k_count<<<PB, 1024, 0, stream>>>(src, dst, cntd, cnts);
    k_binscan<<<NBIN_D, 256, 0, stream>>>(cntd, NBIN_D, offd, totd);
    k_binscan<<<NBIN_S, 256, 0, stream>>>(cnts, NBIN_S, offs, tots);
    k_scan_small<<<1, 256, 0, stream>>>(totd, NBIN_D, bpd);
    k_scan_small<<<1, 256, 0, stream>>>(tots, NBIN_S, bps);
    k_fill<<<PB, 1024, 0, stream>>>(src, dst, offd, offs, bpd, bps, rec, srcb);
    k_ci<<<NBIN_S, 256, 0, stream>>>(srcb, bps, feat, ci, sfeat, prescale ? 1 : 0);
    k_csr<<<NBIN_D, 256, 0, stream>>>(rec, bpd, rptr);
    if (prescale)
        k_gcn<true><<<(N_NODES + 3) / 4, 256, 0, stream>>>(
            rptr, (const int*)rec, ci, sfeat, feat, W, b, out);
    else
        k_gcn<false><<<(N_NODES + 3) / 4, 256, 0, stream>>>(
            rptr, (const int*)rec, ci, sfeat, feat, W, b, out);
}

// Round 9
// 190.723 us; speedup vs baseline: 1.3630x; 1.3630x over previous
//
#include <hip/hip_runtime.h>

#define N_NODES 50000
#define N_EDGES 1600000
#define D 48

#define EPB 8192            // edges per count/fill block
#define PB  196             // ceil(N_EDGES/EPB)
#define NPB_D 64
#define NBIN_D 782          // ceil(50000/64)
#define NPB_S 256
#define NBIN_S 196          // ceil(50000/256)

// ---------- workspace layout (bytes), total ~9.94 MB ----------
#define RECD_OFF  0          // u32[1.6M] dst-binned packed (src<<6)|dlocal; becomes col[] after k_csr
#define SRCB_OFF  6400000    // u8 [1.6M] src-binned (src & 255)
#define CI_OFF    8000000    // f32[50000]
#define CNTD_OFF  8200000    // int[PB][NBIN_D]
#define CNTS_OFF  8813088    // int[PB][NBIN_S]
#define OFFD_OFF  8966752    // int[NBIN_D][PB]
#define OFFS_OFF  9579840    // int[NBIN_S][PB]
#define TOTD_OFF  9733504    // int[NBIN_D]
#define TOTS_OFF  9736632    // int[NBIN_S]
#define BPD_OFF   9737416    // int[NBIN_D+1]
#define BPS_OFF   9740548    // int[NBIN_S+1]
#define RPTR_OFF  9741336    // int[50001]

__global__ __launch_bounds__(1024) void k_count(const int* __restrict__ src,
                                                const int* __restrict__ dst,
                                                int* __restrict__ cntd,
                                                int* __restrict__ cnts) {
    __shared__ int cd[NBIN_D];
    __shared__ int cs[NBIN_S];
    int tid = threadIdx.x;
    for (int i = tid; i < NBIN_D; i += 1024) cd[i] = 0;
    for (int i = tid; i < NBIN_S; i += 1024) cs[i] = 0;
    __syncthreads();
    int base = blockIdx.x * EPB;
    int end = min(base + EPB, N_EDGES);
    for (int e = base + tid; e < end; e += 1024) {
        atomicAdd(&cd[dst[e] >> 6], 1);
        atomicAdd(&cs[src[e] >> 8], 1);
    }
    __syncthreads();
    for (int i = tid; i < NBIN_D; i += 1024) cntd[blockIdx.x * NBIN_D + i] = cd[i];
    for (int i = tid; i < NBIN_S; i += 1024) cnts[blockIdx.x * NBIN_S + i] = cs[i];
}

// one block per bin (dst bins then src bins): exclusive scan over PB block-counts
__global__ __launch_bounds__(256) void k_binscan(const int* __restrict__ cntd,
                                                 const int* __restrict__ cnts,
                                                 int* __restrict__ offd,
                                                 int* __restrict__ offs,
                                                 int* __restrict__ totd,
                                                 int* __restrict__ tots) {
    __shared__ int ts[256];
    int t = threadIdx.x, g = blockIdx.x;
    const int* cntT; int* off; int* tot; int nbin, bin;
    if (g < NBIN_D) { cntT = cntd; off = offd; tot = totd; nbin = NBIN_D; bin = g; }
    else            { cntT = cnts; off = offs; tot = tots; nbin = NBIN_S; bin = g - NBIN_D; }
    int v = (t < PB) ? cntT[t * nbin + bin] : 0;
    ts[t] = v;
    __syncthreads();
    for (int o = 1; o < 256; o <<= 1) {
        int x = (t >= o) ? ts[t - o] : 0;
        __syncthreads();
        ts[t] += x;
        __syncthreads();
    }
    int incl = ts[t];
    if (t < PB) off[bin * PB + t] = incl - v;
    if (t == 255) tot[bin] = incl;
}

// block 0: scan totd[NBIN_D] -> bpd ; block 1: scan tots[NBIN_S] -> bps
__global__ __launch_bounds__(256) void k_scan_small(const int* __restrict__ totd,
                                                    const int* __restrict__ tots,
                                                    int* __restrict__ bpd,
                                                    int* __restrict__ bps) {
    __shared__ int ts[256];
    const int* in; int* out; int n;
    if (blockIdx.x == 0) { in = totd; out = bpd; n = NBIN_D; }
    else                 { in = tots; out = bps; n = NBIN_S; }
    int t = threadIdx.x;
    int base = t * 4;
    int a0 = (base + 0 < n) ? in[base + 0] : 0;
    int a1 = (base + 1 < n) ? in[base + 1] : 0;
    int a2 = (base + 2 < n) ? in[base + 2] : 0;
    int a3 = (base + 3 < n) ? in[base + 3] : 0;
    int tot4 = a0 + a1 + a2 + a3;
    ts[t] = tot4;
    __syncthreads();
    for (int o = 1; o < 256; o <<= 1) {
        int x = (t >= o) ? ts[t - o] : 0;
        __syncthreads();
        ts[t] += x;
        __syncthreads();
    }
    int excl = ts[t] - tot4;
    if (base + 0 < n) out[base + 0] = excl;
    if (base + 1 < n) out[base + 1] = excl + a0;
    if (base + 2 < n) out[base + 2] = excl + a0 + a1;
    if (base + 3 < n) out[base + 3] = excl + a0 + a1 + a2;
    if (t == 255) out[n] = ts[255];
}

__global__ __launch_bounds__(1024) void k_fill(const int* __restrict__ src,
                                               const int* __restrict__ dst,
                                               const int* __restrict__ offd,
                                               const int* __restrict__ offs,
                                               const int* __restrict__ bpd,
                                               const int* __restrict__ bps,
                                               unsigned int* __restrict__ rec,
                                               unsigned char* __restrict__ srcb) {
    __shared__ int curd[NBIN_D];
    __shared__ int curs[NBIN_S];
    int tid = threadIdx.x, blk = blockIdx.x;
    for (int i = tid; i < NBIN_D; i += 1024) curd[i] = bpd[i] + offd[i * PB + blk];
    for (int i = tid; i < NBIN_S; i += 1024) curs[i] = bps[i] + offs[i * PB + blk];
    __syncthreads();
    int base = blk * EPB;
    int end = min(base + EPB, N_EDGES);
    for (int e = base + tid; e < end; e += 1024) {
        int s = src[e], d = dst[e];
        int pd = atomicAdd(&curd[d >> 6], 1);
        rec[pd] = ((unsigned int)s << 6) | (unsigned int)(d & 63);
        int ps = atomicAdd(&curs[s >> 8], 1);
        srcb[ps] = (unsigned char)s;
    }
}

// one block per src-bin: LDS out-degree histogram -> ci
__global__ __launch_bounds__(256) void k_ci(const unsigned char* __restrict__ srcb,
                                            const int* __restrict__ bps,
                                            float* __restrict__ ci) {
    __shared__ int cnt[NPB_S];
    int t = threadIdx.x, bin = blockIdx.x;
    cnt[t] = 0;
    __syncthreads();
    int beg = bps[bin], end = bps[bin + 1];
    for (int j = beg + t; j < end; j += 256)
        atomicAdd(&cnt[srcb[j]], 1);
    __syncthreads();
    int n = bin * NPB_S + t;
    if (n < N_NODES) ci[n] = rsqrtf(fmaxf((float)cnt[t], 1.0f));
}

// one block per dst-bin: stage bin edges in LDS, count+scan in-degrees ->
// rowptr, then reorder in place (rec -> per-node-grouped col of src ids).
__global__ __launch_bounds__(256) void k_csr(unsigned int* __restrict__ rec,
                                             const int* __restrict__ bpd,
                                             int* __restrict__ rowptr) {
    __shared__ unsigned int ebuf[3072];   // bin edge count ~2048, sigma ~45
    __shared__ int ideg[NPB_D];
    __shared__ int off[NPB_D];
    __shared__ int cur[NPB_D];
    int tid = threadIdx.x, bin = blockIdx.x;
    int beg = bpd[bin], end = bpd[bin + 1];
    int cnt = end - beg;
    if (cnt > 3072) cnt = 3072;           // unreachable; guards LDS OOB
    if (tid < NPB_D) { ideg[tid] = 0; cur[tid] = 0; }
    __syncthreads();
    for (int j = tid; j < cnt; j += 256) {
        unsigned int r = rec[beg + j];
        ebuf[j] = r;
        atomicAdd(&ideg[r & 63], 1);
    }
    __syncthreads();
    if (tid < NPB_D) {
        int v = ideg[tid];
        int incl = v;
        for (int o = 1; o < 64; o <<= 1) {
            int u = __shfl_up(incl, o);
            if (tid >= o) incl += u;
        }
        int ex = incl - v;
        off[tid] = ex;
        int n = bin * NPB_D + tid;
        if (n < N_NODES) rowptr[n] = beg + ex;
    }
    if (bin == NBIN_D - 1 && tid == 0) rowptr[N_NODES] = N_EDGES;
    __syncthreads();
    for (int j = tid; j < cnt; j += 256) {
        unsigned int r = ebuf[j];
        int dl = r & 63;
        int p = atomicAdd(&cur[dl], 1);
        rec[beg + off[dl] + p] = r >> 6;   // now plain src id
    }
}

// one wave per dst node. float4-lane gather: lane L = edge-slot L/12, dims
// 4*(L%12)..+4. One float4 wave-load covers 5 edge rows (60 lanes x 16B).
__global__ __launch_bounds__(256) void k_gcn(
    const int* __restrict__ rowptr, const int* __restrict__ col,
    const float* __restrict__ ci, const float* __restrict__ feat,
    const float* __restrict__ W, const float* __restrict__ b,
    float* __restrict__ out) {
    __shared__ float Wl[D * 49];
    __shared__ float bl[D];
    __shared__ float hl[4 * D];
    int tid = threadIdx.x;

    for (int i = tid; i < D * D; i += 256) {
        int od = i / D, k = i - od * D;
        Wl[od * 49 + k] = W[i];
    }
    if (tid < D) bl[tid] = b[tid];

    int wave = tid >> 6;
    int lane = tid & 63;
    int n = blockIdx.x * 4 + wave;
    int eslot = lane / 12;               // 0..5 (slot 5 = lanes 60..63, inactive)
    int d4 = lane - eslot * 12;          // 0..11
    bool lane_ok = (lane < 60);

    int beg = 0, end = 0;
    if (n < N_NODES) { beg = rowptr[n]; end = rowptr[n + 1]; }
    int indeg = end - beg;

    const float4* feat4 = (const float4*)feat;

    float4 acc = make_float4(0.0f, 0.0f, 0.0f, 0.0f);
    for (int j0 = beg; j0 < end; j0 += 60) {
        int jn = min(60, end - j0);
        // one col load + one ci gather per <=60 edges, broadcast via shfl
        int colv = (lane < jn) ? col[j0 + lane] : 0;
        float civ = (lane < jn) ? ci[colv] : 0.0f;
        for (int i = 0; i < 60 && i < jn; i += 5) {
            int ei = i + eslot;
            int s = __shfl(colv, ei);
            float c = __shfl(civ, ei);
            if (lane_ok && ei < jn) {
                float4 f = feat4[(size_t)s * 12 + d4];
                acc.x = fmaf(f.x, c, acc.x);
                acc.y = fmaf(f.y, c, acc.y);
                acc.z = fmaf(f.z, c, acc.z);
                acc.w = fmaf(f.w, c, acc.w);
            }
        }
    }
    // reduce the 5 edge slots onto slot 0 (lanes 0..11).
    // All shfls read the ORIGINAL acc (temps computed before the update) —
    // the in-place strided version double-counts (R8 bug).
    {
        float x1 = __shfl(acc.x, lane + 12), x2 = __shfl(acc.x, lane + 24);
        float x3 = __shfl(acc.x, lane + 36), x4 = __shfl(acc.x, lane + 48);
        float y1 = __shfl(acc.y, lane + 12), y2 = __shfl(acc.y, lane + 24);
        float y3 = __shfl(acc.y, lane + 36), y4 = __shfl(acc.y, lane + 48);
        float z1 = __shfl(acc.z, lane + 12), z2 = __shfl(acc.z, lane + 24);
        float z3 = __shfl(acc.z, lane + 36), z4 = __shfl(acc.z, lane + 48);
        float w1 = __shfl(acc.w, lane + 12), w2 = __shfl(acc.w, lane + 24);
        float w3 = __shfl(acc.w, lane + 36), w4 = __shfl(acc.w, lane + 48);
        acc.x += (x1 + x2) + (x3 + x4);
        acc.y += (y1 + y2) + (y3 + y4);
        acc.z += (z1 + z2) + (z3 + z4);
        acc.w += (w1 + w2) + (w3 + w4);
    }

    if (lane < 12 && n < N_NODES) {
        float4 res;
        if (indeg > 0) {
            float cj = rsqrtf((float)indeg);
            res = make_float4(acc.x * cj, acc.y * cj, acc.z * cj, acc.w * cj);
        } else {
            res = feat4[(size_t)n * 12 + d4];
        }
        *(float4*)(hl + wave * D + d4 * 4) = res;
    }
    __syncthreads();

    if (tid < 4 * D) {
        int nl = tid / D, od = tid - nl * D;
        int n2 = blockIdx.x * 4 + nl;
        if (n2 < N_NODES) {
            float a2 = bl[od];
            #pragma unroll
            for (int k = 0; k < D; k++)
                a2 = fmaf(hl[nl * D + k], Wl[od * 49 + k], a2);
            out[(size_t)n2 * D + od] = fmaxf(a2, 0.0f);
        }
    }
}

extern "C" void kernel_launch(void* const* d_in, const int* in_sizes, int n_in,
                              void* d_out, int out_size, void* d_ws, size_t ws_size,
                              hipStream_t stream) {
    const float* feat = (const float*)d_in[0];
    const int*   src  = (const int*)d_in[1];
    const int*   dst  = (const int*)d_in[2];
    const float* W    = (const float*)d_in[3];
    const float* b    = (const float*)d_in[4];
    float* out = (float*)d_out;

    char* ws = (char*)d_ws;
    unsigned int*  rec  = (unsigned int*)(ws + RECD_OFF);
    unsigned char* srcb = (unsigned char*)(ws + SRCB_OFF);
    float* ci   = (float*)(ws + CI_OFF);
    int*   cntd = (int*)(ws + CNTD_OFF);
    int*   cnts = (int*)(ws + CNTS_OFF);
    int*   offd = (int*)(ws + OFFD_OFF);
    int*   offs = (int*)(ws + OFFS_OFF);
    int*   totd = (int*)(ws + TOTD_OFF);
    int*   tots = (int*)(ws + TOTS_OFF);
    int*   bpd  = (int*)(ws + BPD_OFF);
    int*   bps  = (int*)(ws + BPS_OFF);
    int*   rptr = (int*)(ws + RPTR_OFF);

    k_count<<<PB, 1024, 0, stream>>>(src, dst, cntd, cnts);
    k_binscan<<<NBIN_D + NBIN_S, 256, 0, stream>>>(cntd, cnts, offd, offs, totd, tots);
    k_scan_small<<<2, 256, 0, stream>>>(totd, tots, bpd, bps);
    k_fill<<<PB, 1024, 0, stream>>>(src, dst, offd, offs, bpd, bps, rec, srcb);
    k_ci<<<NBIN_S, 256, 0, stream>>>(srcb, bps, ci);
    k_csr<<<NBIN_D, 256, 0, stream>>>(rec, bpd, rptr);
    k_gcn<<<(N_NODES + 3) / 4, 256, 0, stream>>>(rptr, (const int*)rec, ci, feat, W, b, out);
}

// Round 10
// 173.495 us; speedup vs baseline: 1.4984x; 1.0993x over previous
//
#include <hip/hip_runtime.h>

#define N_NODES 50000
#define N_EDGES 1600000
#define D 48

#define EPB 8192            // edges per count/fill block
#define PB  196             // ceil(N_EDGES/EPB)
#define NPB_D 64
#define NBIN_D 782          // ceil(50000/64)
#define NPB_S 256
#define NBIN_S 196          // ceil(50000/256)

#define EMAX 3072           // per-bin edge cap (mean 2048, sigma 45 -> 22 sigma)
#define HS 52               // h/W LDS stride (16B-aligned, bank-spread)

// ---------- workspace layout (bytes), total ~9.74 MB (proven <=9.94) ----------
#define RECD_OFF  0          // u32[1.6M] dst-binned packed (src<<6)|dlocal
#define SRCB_OFF  6400000    // u8 [1.6M] src-binned (src & 255)
#define CI_OFF    8000000    // f32[50000]
#define CNTD_OFF  8200000    // int[PB][NBIN_D]
#define CNTS_OFF  8813088    // int[PB][NBIN_S]
#define OFFD_OFF  8966752    // int[NBIN_D][PB]
#define OFFS_OFF  9579840    // int[NBIN_S][PB]
#define TOTD_OFF  9733504    // int[NBIN_D]
#define TOTS_OFF  9736632    // int[NBIN_S]
#define BPD_OFF   9737416    // int[NBIN_D+1]
#define BPS_OFF   9740548    // int[NBIN_S+1]

__global__ __launch_bounds__(1024) void k_count(const int* __restrict__ src,
                                                const int* __restrict__ dst,
                                                int* __restrict__ cntd,
                                                int* __restrict__ cnts) {
    __shared__ int cd[NBIN_D];
    __shared__ int cs[NBIN_S];
    int tid = threadIdx.x;
    for (int i = tid; i < NBIN_D; i += 1024) cd[i] = 0;
    for (int i = tid; i < NBIN_S; i += 1024) cs[i] = 0;
    __syncthreads();
    int base = blockIdx.x * EPB;
    int end = min(base + EPB, N_EDGES);
    for (int e = base + tid; e < end; e += 1024) {
        atomicAdd(&cd[dst[e] >> 6], 1);
        atomicAdd(&cs[src[e] >> 8], 1);
    }
    __syncthreads();
    for (int i = tid; i < NBIN_D; i += 1024) cntd[blockIdx.x * NBIN_D + i] = cd[i];
    for (int i = tid; i < NBIN_S; i += 1024) cnts[blockIdx.x * NBIN_S + i] = cs[i];
}

// one block per bin (dst bins then src bins): exclusive scan over PB block-counts
__global__ __launch_bounds__(256) void k_binscan(const int* __restrict__ cntd,
                                                 const int* __restrict__ cnts,
                                                 int* __restrict__ offd,
                                                 int* __restrict__ offs,
                                                 int* __restrict__ totd,
                                                 int* __restrict__ tots) {
    __shared__ int ts[256];
    int t = threadIdx.x, g = blockIdx.x;
    const int* cntT; int* off; int* tot; int nbin, bin;
    if (g < NBIN_D) { cntT = cntd; off = offd; tot = totd; nbin = NBIN_D; bin = g; }
    else            { cntT = cnts; off = offs; tot = tots; nbin = NBIN_S; bin = g - NBIN_D; }
    int v = (t < PB) ? cntT[t * nbin + bin] : 0;
    ts[t] = v;
    __syncthreads();
    for (int o = 1; o < 256; o <<= 1) {
        int x = (t >= o) ? ts[t - o] : 0;
        __syncthreads();
        ts[t] += x;
        __syncthreads();
    }
    int incl = ts[t];
    if (t < PB) off[bin * PB + t] = incl - v;
    if (t == 255) tot[bin] = incl;
}

// block 0: scan totd[NBIN_D] -> bpd ; block 1: scan tots[NBIN_S] -> bps
__global__ __launch_bounds__(256) void k_scan_small(const int* __restrict__ totd,
                                                    const int* __restrict__ tots,
                                                    int* __restrict__ bpd,
                                                    int* __restrict__ bps) {
    __shared__ int ts[256];
    const int* in; int* out; int n;
    if (blockIdx.x == 0) { in = totd; out = bpd; n = NBIN_D; }
    else                 { in = tots; out = bps; n = NBIN_S; }
    int t = threadIdx.x;
    int base = t * 4;
    int a0 = (base + 0 < n) ? in[base + 0] : 0;
    int a1 = (base + 1 < n) ? in[base + 1] : 0;
    int a2 = (base + 2 < n) ? in[base + 2] : 0;
    int a3 = (base + 3 < n) ? in[base + 3] : 0;
    int tot4 = a0 + a1 + a2 + a3;
    ts[t] = tot4;
    __syncthreads();
    for (int o = 1; o < 256; o <<= 1) {
        int x = (t >= o) ? ts[t - o] : 0;
        __syncthreads();
        ts[t] += x;
        __syncthreads();
    }
    int excl = ts[t] - tot4;
    if (base + 0 < n) out[base + 0] = excl;
    if (base + 1 < n) out[base + 1] = excl + a0;
    if (base + 2 < n) out[base + 2] = excl + a0 + a1;
    if (base + 3 < n) out[base + 3] = excl + a0 + a1 + a2;
    if (t == 255) out[n] = ts[255];
}

__global__ __launch_bounds__(1024) void k_fill(const int* __restrict__ src,
                                               const int* __restrict__ dst,
                                               const int* __restrict__ offd,
                                               const int* __restrict__ offs,
                                               const int* __restrict__ bpd,
                                               const int* __restrict__ bps,
                                               unsigned int* __restrict__ rec,
                                               unsigned char* __restrict__ srcb) {
    __shared__ int curd[NBIN_D];
    __shared__ int curs[NBIN_S];
    int tid = threadIdx.x, blk = blockIdx.x;
    for (int i = tid; i < NBIN_D; i += 1024) curd[i] = bpd[i] + offd[i * PB + blk];
    for (int i = tid; i < NBIN_S; i += 1024) curs[i] = bps[i] + offs[i * PB + blk];
    __syncthreads();
    int base = blk * EPB;
    int end = min(base + EPB, N_EDGES);
    for (int e = base + tid; e < end; e += 1024) {
        int s = src[e], d = dst[e];
        int pd = atomicAdd(&curd[d >> 6], 1);
        rec[pd] = ((unsigned int)s << 6) | (unsigned int)(d & 63);
        int ps = atomicAdd(&curs[s >> 8], 1);
        srcb[ps] = (unsigned char)s;
    }
}

// one block per src-bin: LDS out-degree histogram -> ci
__global__ __launch_bounds__(256) void k_ci(const unsigned char* __restrict__ srcb,
                                            const int* __restrict__ bps,
                                            float* __restrict__ ci) {
    __shared__ int cnt[NPB_S];
    int t = threadIdx.x, bin = blockIdx.x;
    cnt[t] = 0;
    __syncthreads();
    int beg = bps[bin], end = bps[bin + 1];
    for (int j = beg + t; j < end; j += 256)
        atomicAdd(&cnt[srcb[j]], 1);
    __syncthreads();
    int n = bin * NPB_S + t;
    if (n < N_NODES) ci[n] = rsqrtf(fmaxf((float)cnt[t], 1.0f));
}

// Fused CSR-build + gather + GEMM: one block (16 waves) per 64-node dst-bin.
// Phase A: records -> regs, LDS histogram+scan, reorder into LDS col buffer.
// Phase B: wave-per-node float4-lane gather (4 nodes/wave sequentially).
// Phase C: 48x48 GEMM via ds_read_b128 at stride 52 (bank-spread), ReLU, store.
__global__ __launch_bounds__(1024, 8) void k_gcn(
    const unsigned int* __restrict__ rec, const int* __restrict__ bpd,
    const float* __restrict__ ci, const float* __restrict__ feat,
    const float* __restrict__ W, const float* __restrict__ b,
    float* __restrict__ out) {
    __shared__ int   colb[EMAX];        // 12.3 KB: reordered local col (src ids)
    __shared__ float hl[NPB_D * HS];    // 13.3 KB
    __shared__ float Wl[D * HS];        // 10.0 KB
    __shared__ float bl[D];
    __shared__ int   ideg[NPB_D];
    __shared__ int   off[NPB_D];
    __shared__ int   cur[NPB_D];
    int tid = threadIdx.x, bin = blockIdx.x;

    int beg = bpd[bin], end = bpd[bin + 1];
    int cnt = end - beg;
    if (cnt > EMAX) cnt = EMAX;         // unreachable; guards LDS OOB

    for (int i = tid; i < D * D; i += 1024) Wl[(i / D) * HS + (i % D)] = W[i];
    if (tid < D) bl[tid] = b[tid];
    if (tid < NPB_D) { ideg[tid] = 0; cur[tid] = 0; }
    __syncthreads();

    // ---- Phase A: histogram + scan + reorder (records held in registers) ----
    unsigned int r0 = 0, r1 = 0, r2 = 0;
    int j0 = tid, j1 = tid + 1024, j2 = tid + 2048;
    if (j0 < cnt) { r0 = rec[beg + j0]; atomicAdd(&ideg[r0 & 63], 1); }
    if (j1 < cnt) { r1 = rec[beg + j1]; atomicAdd(&ideg[r1 & 63], 1); }
    if (j2 < cnt) { r2 = rec[beg + j2]; atomicAdd(&ideg[r2 & 63], 1); }
    __syncthreads();
    if (tid < NPB_D) {
        int v = ideg[tid];
        int incl = v;
        for (int o = 1; o < 64; o <<= 1) {
            int u = __shfl_up(incl, o);
            if (tid >= o) incl += u;
        }
        off[tid] = incl - v;
    }
    __syncthreads();
    if (j0 < cnt) { int dl = r0 & 63; int p = atomicAdd(&cur[dl], 1); colb[off[dl] + p] = (int)(r0 >> 6); }
    if (j1 < cnt) { int dl = r1 & 63; int p = atomicAdd(&cur[dl], 1); colb[off[dl] + p] = (int)(r1 >> 6); }
    if (j2 < cnt) { int dl = r2 & 63; int p = atomicAdd(&cur[dl], 1); colb[off[dl] + p] = (int)(r2 >> 6); }
    __syncthreads();

    // ---- Phase B: gather. lane = edge-slot(0..4)*12 + d4; float4 per lane ----
    int wave = tid >> 6;
    int lane = tid & 63;
    int eslot = lane / 12;              // 0..5 (slot 5 inactive)
    int d4 = lane - eslot * 12;         // 0..11
    bool lane_ok = (lane < 60);
    const float4* feat4 = (const float4*)feat;

    for (int q = 0; q < 4; ++q) {
        int nl = wave * 4 + q;
        int n = bin * NPB_D + nl;
        int cb = off[nl];
        int deg = ideg[nl];

        float4 acc = make_float4(0.0f, 0.0f, 0.0f, 0.0f);
        for (int c0 = 0; c0 < deg; c0 += 60) {
            int jn = min(60, deg - c0);
            int colv = (lane < jn) ? colb[cb + c0 + lane] : 0;
            float civ = (lane < jn) ? ci[colv] : 0.0f;
            for (int i = 0; i < jn; i += 5) {
                int ei = i + eslot;
                int s = __shfl(colv, ei);
                float c = __shfl(civ, ei);
                if (lane_ok && ei < jn) {
                    float4 f = feat4[(size_t)s * 12 + d4];
                    acc.x = fmaf(f.x, c, acc.x);
                    acc.y = fmaf(f.y, c, acc.y);
                    acc.z = fmaf(f.z, c, acc.z);
                    acc.w = fmaf(f.w, c, acc.w);
                }
            }
        }
        // reduce 5 edge slots onto lanes 0..11 (temps BEFORE update: no aliasing)
        {
            float x1 = __shfl(acc.x, lane + 12), x2 = __shfl(acc.x, lane + 24);
            float x3 = __shfl(acc.x, lane + 36), x4 = __shfl(acc.x, lane + 48);
            float y1 = __shfl(acc.y, lane + 12), y2 = __shfl(acc.y, lane + 24);
            float y3 = __shfl(acc.y, lane + 36), y4 = __shfl(acc.y, lane + 48);
            float z1 = __shfl(acc.z, lane + 12), z2 = __shfl(acc.z, lane + 24);
            float z3 = __shfl(acc.z, lane + 36), z4 = __shfl(acc.z, lane + 48);
            float w1 = __shfl(acc.w, lane + 12), w2 = __shfl(acc.w, lane + 24);
            float w3 = __shfl(acc.w, lane + 36), w4 = __shfl(acc.w, lane + 48);
            acc.x += (x1 + x2) + (x3 + x4);
            acc.y += (y1 + y2) + (y3 + y4);
            acc.z += (z1 + z2) + (z3 + z4);
            acc.w += (w1 + w2) + (w3 + w4);
        }
        if (lane < 12 && n < N_NODES) {
            float4 res;
            if (deg > 0) {
                float cj = rsqrtf((float)deg);
                res = make_float4(acc.x * cj, acc.y * cj, acc.z * cj, acc.w * cj);
            } else {
                res = feat4[(size_t)n * 12 + d4];
            }
            *(float4*)(hl + nl * HS + d4 * 4) = res;
        }
    }
    __syncthreads();

    // ---- Phase C: out = relu(h @ W^T + b), b128 LDS reads ----
    {
        int nl = tid >> 4;              // 0..63
        int c = tid & 15;               // od = c, c+16, c+32
        int n = bin * NPB_D + nl;
        if (n < N_NODES) {
            float a0 = bl[c], a1 = bl[c + 16], a2 = bl[c + 32];
            #pragma unroll
            for (int k4 = 0; k4 < 12; ++k4) {
                float4 hv = *(const float4*)(hl + nl * HS + k4 * 4);
                float4 w0 = *(const float4*)(Wl + c * HS + k4 * 4);
                float4 w1 = *(const float4*)(Wl + (c + 16) * HS + k4 * 4);
                float4 w2 = *(const float4*)(Wl + (c + 32) * HS + k4 * 4);
                a0 = fmaf(hv.x, w0.x, a0); a0 = fmaf(hv.y, w0.y, a0);
                a0 = fmaf(hv.z, w0.z, a0); a0 = fmaf(hv.w, w0.w, a0);
                a1 = fmaf(hv.x, w1.x, a1); a1 = fmaf(hv.y, w1.y, a1);
                a1 = fmaf(hv.z, w1.z, a1); a1 = fmaf(hv.w, w1.w, a1);
                a2 = fmaf(hv.x, w2.x, a2); a2 = fmaf(hv.y, w2.y, a2);
                a2 = fmaf(hv.z, w2.z, a2); a2 = fmaf(hv.w, w2.w, a2);
            }
            float* op = out + (size_t)n * D;
            op[c]      = fmaxf(a0, 0.0f);
            op[c + 16] = fmaxf(a1, 0.0f);
            op[c + 32] = fmaxf(a2, 0.0f);
        }
    }
}

extern "C" void kernel_launch(void* const* d_in, const int* in_sizes, int n_in,
                              void* d_out, int out_size, void* d_ws, size_t ws_size,
                              hipStream_t stream) {
    const float* feat = (const float*)d_in[0];
    const int*   src  = (const int*)d_in[1];
    const int*   dst  = (const int*)d_in[2];
    const float* W    = (const float*)d_in[3];
    const float* b    = (const float*)d_in[4];
    float* out = (float*)d_out;

    char* ws = (char*)d_ws;
    unsigned int*  rec  = (unsigned int*)(ws + RECD_OFF);
    unsigned char* srcb = (unsigned char*)(ws + SRCB_OFF);
    float* ci   = (float*)(ws + CI_OFF);
    int*   cntd = (int*)(ws + CNTD_OFF);
    int*   cnts = (int*)(ws + CNTS_OFF);
    int*   offd = (int*)(ws + OFFD_OFF);
    int*   offs = (int*)(ws + OFFS_OFF);
    int*   totd = (int*)(ws + TOTD_OFF);
    int*   tots = (int*)(ws + TOTS_OFF);
    int*   bpd  = (int*)(ws + BPD_OFF);
    int*   bps  = (int*)(ws + BPS_OFF);

    k_count<<<PB, 1024, 0, stream>>>(src, dst, cntd, cnts);
    k_binscan<<<NBIN_D + NBIN_S, 256, 0, stream>>>(cntd, cnts, offd, offs, totd, tots);
    k_scan_small<<<2, 256, 0, stream>>>(totd, tots, bpd, bps);
    k_fill<<<PB, 1024, 0, stream>>>(src, dst, offd, offs, bpd, bps, rec, srcb);
    k_ci<<<NBIN_S, 256, 0, stream>>>(srcb, bps, ci);
    k_gcn<<<NBIN_D, 1024, 0, stream>>>(rec, bpd, ci, feat, W, b, out);
}

// Round 11
// 159.471 us; speedup vs baseline: 1.6301x; 1.0879x over previous
//
#include <hip/hip_runtime.h>

#define N_NODES 50000
#define N_EDGES 1600000
#define D 48

#define EPB 8192            // edges per prep block
#define PB  196             // ceil(N_EDGES/EPB)
#define NPB_D 64
#define NBIN_D 782          // ceil(50000/64)
#define NPB_S 256
#define NBIN_S 196          // ceil(50000/256)

#define EMAX 3072           // per-dst-bin edge cap (mean 2048, sigma ~45)
#define HS 52               // h/W LDS stride (16B-aligned, bank-spread; proven R10)

// ---------- workspace layout (bytes), total ~8.61 MB ----------
#define RECD_OFF  0          // u32[PB*EPB] block-major: (src<<6)|dlocal, grouped by dst-bin within block
#define SRCB_OFF  6422528    // u8 [PB*EPB] block-major: src&255, grouped by src-bin within block
#define CI_OFF    8028160    // f32[50000]
#define OFFLD_OFF 8228160    // u16[PB][NBIN_D+1] per-block exclusive run offsets (dst bins)
#define OFFLS_OFF 8535096    // u16[PB][NBIN_S+1] per-block exclusive run offsets (src bins)

// One kernel = count + scan + scatter, all block-local. Coalesced output only.
__global__ __launch_bounds__(1024) void k_prep(const int* __restrict__ src,
                                               const int* __restrict__ dst,
                                               unsigned int* __restrict__ rec,
                                               unsigned char* __restrict__ srcb,
                                               unsigned short* __restrict__ offld,
                                               unsigned short* __restrict__ offls) {
    __shared__ int cd[NBIN_D];                  // histogram, then cursor
    __shared__ int cs[NBIN_S];
    __shared__ int scan[1024];
    __shared__ alignas(16) unsigned int  bufd[EPB];
    __shared__ alignas(16) unsigned char bufs[EPB];
    int tid = threadIdx.x, p = blockIdx.x;
    int base = p * EPB;

    int sv[8], dv[8];
    bool ok[8];
    #pragma unroll
    for (int k = 0; k < 8; ++k) {
        int e = base + tid + k * 1024;
        ok[k] = (e < N_EDGES);
        sv[k] = ok[k] ? src[e] : 0;
        dv[k] = ok[k] ? dst[e] : 0;
    }

    for (int i = tid; i < NBIN_D; i += 1024) cd[i] = 0;
    for (int i = tid; i < NBIN_S; i += 1024) cs[i] = 0;
    __syncthreads();
    #pragma unroll
    for (int k = 0; k < 8; ++k) {
        if (ok[k]) {
            atomicAdd(&cd[dv[k] >> 6], 1);
            atomicAdd(&cs[sv[k] >> 8], 1);
        }
    }
    __syncthreads();

    // one fused Hillis-Steele scan over [cd | cs] (782 + 196 = 978 <= 1024)
    int own = 0;
    if (tid < NBIN_D) own = cd[tid];
    else if (tid < NBIN_D + NBIN_S) own = cs[tid - NBIN_D];
    scan[tid] = own;
    __syncthreads();
    for (int o = 1; o < 1024; o <<= 1) {
        int x = (tid >= o) ? scan[tid - o] : 0;
        __syncthreads();
        scan[tid] += x;
        __syncthreads();
    }
    int incl = scan[tid];
    int cdt = scan[NBIN_D - 1];                 // total dst-side count
    __syncthreads();                            // (reads of scan done)

    if (tid < NBIN_D) {
        int ex = incl - own;
        offld[p * (NBIN_D + 1) + tid] = (unsigned short)ex;
        cd[tid] = ex;                           // cursor
        if (tid == NBIN_D - 1) offld[p * (NBIN_D + 1) + NBIN_D] = (unsigned short)incl;
    } else if (tid < NBIN_D + NBIN_S) {
        int t = tid - NBIN_D;
        int ex = (incl - cdt) - own;
        offls[p * (NBIN_S + 1) + t] = (unsigned short)ex;
        cs[t] = ex;                             // cursor
        if (t == NBIN_S - 1) offls[p * (NBIN_S + 1) + NBIN_S] = (unsigned short)(incl - cdt);
    }
    __syncthreads();

    #pragma unroll
    for (int k = 0; k < 8; ++k) {
        if (ok[k]) {
            int s = sv[k], d = dv[k];
            int pd = atomicAdd(&cd[d >> 6], 1);
            bufd[pd] = ((unsigned int)s << 6) | (unsigned int)(d & 63);
            int ps = atomicAdd(&cs[s >> 8], 1);
            bufs[ps] = (unsigned char)s;
        }
    }
    __syncthreads();

    // coalesced full-line streams out
    int4* ro = (int4*)(rec + base);
    const int4* bi = (const int4*)bufd;
    for (int i = tid; i < EPB / 4; i += 1024) ro[i] = bi[i];
    unsigned int* so = (unsigned int*)(srcb + base);
    const unsigned int* bs = (const unsigned int*)bufs;
    for (int i = tid; i < EPB / 4; i += 1024) so[i] = bs[i];
}

// one block per src-bin: gather its PB runs, LDS histogram -> ci
__global__ __launch_bounds__(512) void k_ci(const unsigned char* __restrict__ srcb,
                                            const unsigned short* __restrict__ offls,
                                            float* __restrict__ ci) {
    __shared__ int cnt[NPB_S];
    int tid = threadIdx.x, sb = blockIdx.x;
    for (int i = tid; i < NPB_S; i += 512) cnt[i] = 0;
    __syncthreads();
    int wave = tid >> 6, lane = tid & 63;
    for (int p = wave; p < PB; p += 8) {
        int beg = offls[p * (NBIN_S + 1) + sb];
        int end = offls[p * (NBIN_S + 1) + sb + 1];
        for (int j = beg + lane; j < end; j += 64)
            atomicAdd(&cnt[srcb[p * EPB + j]], 1);
    }
    __syncthreads();
    int n = sb * NPB_S + tid;
    if (tid < NPB_S && n < N_NODES)
        ci[n] = rsqrtf(fmaxf((float)cnt[tid], 1.0f));
}

// Fused CSR-build + gather + GEMM: one block (16 waves) per 64-node dst-bin.
// Phase A: gather this bin's PB runs (binary search over LDS run table),
//          histogram + scan + reorder into LDS col buffer.
// Phase B: wave-per-node float4-lane gather (4 nodes/wave sequentially).
// Phase C: 48x48 GEMM via ds_read_b128 at stride 52, ReLU, coalesced store.
__global__ __launch_bounds__(1024, 8) void k_gcn(
    const unsigned int* __restrict__ rec, const unsigned short* __restrict__ offld,
    const float* __restrict__ ci, const float* __restrict__ feat,
    const float* __restrict__ W, const float* __restrict__ b,
    float* __restrict__ out) {
    __shared__ int   craw[EMAX];        // raw records (arbitrary order)
    __shared__ int   colb[EMAX];        // reordered local col (src ids)
    __shared__ float hl[NPB_D * HS];
    __shared__ float Wl[D * HS];
    __shared__ float bl[D];
    __shared__ int   ideg[NPB_D];
    __shared__ int   off[NPB_D];
    __shared__ int   cur[NPB_D];
    __shared__ int   runoff[PB + 1];    // exclusive scan of run lengths
    __shared__ int   runpos[PB];        // absolute start index in rec
    __shared__ int   rs[256];
    int tid = threadIdx.x, bin = blockIdx.x;

    for (int i = tid; i < D * D; i += 1024) Wl[(i / D) * HS + (i % D)] = W[i];
    if (tid < D) bl[tid] = b[tid];
    if (tid < NPB_D) { ideg[tid] = 0; cur[tid] = 0; }

    // ---- run table + scan of run lengths ----
    int rlen = 0;
    if (tid < PB) {
        int o0 = offld[tid * (NBIN_D + 1) + bin];
        int o1 = offld[tid * (NBIN_D + 1) + bin + 1];
        rlen = o1 - o0;
        runpos[tid] = tid * EPB + o0;
    }
    if (tid < 256) rs[tid] = (tid < PB) ? rlen : 0;
    __syncthreads();
    for (int o = 1; o < 256; o <<= 1) {
        int x = 0;
        if (tid < 256 && tid >= o) x = rs[tid - o];
        __syncthreads();
        if (tid < 256) rs[tid] += x;
        __syncthreads();
    }
    if (tid < PB) runoff[tid] = rs[tid] - rlen;
    if (tid == 0) runoff[PB] = rs[PB - 1];
    __syncthreads();
    int cnt = runoff[PB];
    if (cnt > EMAX) cnt = EMAX;         // unreachable; guards LDS OOB

    // ---- Phase A: gather runs, histogram, scan, reorder ----
    for (int j = tid; j < cnt; j += 1024) {
        int lo = 0, hi = PB - 1;
        while (lo < hi) {
            int mid = (lo + hi + 1) >> 1;
            if (runoff[mid] <= j) lo = mid; else hi = mid - 1;
        }
        unsigned int r = rec[runpos[lo] + (j - runoff[lo])];
        craw[j] = (int)r;
        atomicAdd(&ideg[r & 63], 1);
    }
    __syncthreads();
    if (tid < NPB_D) {
        int v = ideg[tid];
        int incl = v;
        for (int o = 1; o < 64; o <<= 1) {
            int u = __shfl_up(incl, o);
            if (tid >= o) incl += u;
        }
        off[tid] = incl - v;
    }
    __syncthreads();
    for (int j = tid; j < cnt; j += 1024) {
        int r = craw[j];
        int dl = r & 63;
        int p = atomicAdd(&cur[dl], 1);
        colb[off[dl] + p] = r >> 6;
    }
    __syncthreads();

    // ---- Phase B: float4-lane gather ----
    int wave = tid >> 6;
    int lane = tid & 63;
    int eslot = lane / 12;              // 0..5 (slot 5 inactive)
    int d4 = lane - eslot * 12;         // 0..11
    bool lane_ok = (lane < 60);
    const float4* feat4 = (const float4*)feat;

    for (int q = 0; q < 4; ++q) {
        int nl = wave * 4 + q;
        int n = bin * NPB_D + nl;
        int cb = off[nl];
        int deg = ideg[nl];

        float4 acc = make_float4(0.0f, 0.0f, 0.0f, 0.0f);
        for (int c0 = 0; c0 < deg; c0 += 60) {
            int jn = min(60, deg - c0);
            int colv = (lane < jn) ? colb[cb + c0 + lane] : 0;
            float civ = (lane < jn) ? ci[colv] : 0.0f;
            for (int i = 0; i < jn; i += 5) {
                int ei = i + eslot;
                int s = __shfl(colv, ei);
                float c = __shfl(civ, ei);
                if (lane_ok && ei < jn) {
                    float4 f = feat4[(size_t)s * 12 + d4];
                    acc.x = fmaf(f.x, c, acc.x);
                    acc.y = fmaf(f.y, c, acc.y);
                    acc.z = fmaf(f.z, c, acc.z);
                    acc.w = fmaf(f.w, c, acc.w);
                }
            }
        }
        // reduce 5 edge slots onto lanes 0..11 (temps BEFORE update: no aliasing)
        {
            float x1 = __shfl(acc.x, lane + 12), x2 = __shfl(acc.x, lane + 24);
            float x3 = __shfl(acc.x, lane + 36), x4 = __shfl(acc.x, lane + 48);
            float y1 = __shfl(acc.y, lane + 12), y2 = __shfl(acc.y, lane + 24);
            float y3 = __shfl(acc.y, lane + 36), y4 = __shfl(acc.y, lane + 48);
            float z1 = __shfl(acc.z, lane + 12), z2 = __shfl(acc.z, lane + 24);
            float z3 = __shfl(acc.z, lane + 36), z4 = __shfl(acc.z, lane + 48);
            float w1 = __shfl(acc.w, lane + 12), w2 = __shfl(acc.w, lane + 24);
            float w3 = __shfl(acc.w, lane + 36), w4 = __shfl(acc.w, lane + 48);
            acc.x += (x1 + x2) + (x3 + x4);
            acc.y += (y1 + y2) + (y3 + y4);
            acc.z += (z1 + z2) + (z3 + z4);
            acc.w += (w1 + w2) + (w3 + w4);
        }
        if (lane < 12 && n < N_NODES) {
            float4 res;
            if (deg > 0) {
                float cj = rsqrtf((float)deg);
                res = make_float4(acc.x * cj, acc.y * cj, acc.z * cj, acc.w * cj);
            } else {
                res = feat4[(size_t)n * 12 + d4];
            }
            *(float4*)(hl + nl * HS + d4 * 4) = res;
        }
    }
    __syncthreads();

    // ---- Phase C: out = relu(h @ W^T + b), b128 LDS reads ----
    {
        int nl = tid >> 4;              // 0..63
        int c = tid & 15;               // od = c, c+16, c+32
        int n = bin * NPB_D + nl;
        if (n < N_NODES) {
            float a0 = bl[c], a1 = bl[c + 16], a2 = bl[c + 32];
            #pragma unroll
            for (int k4 = 0; k4 < 12; ++k4) {
                float4 hv = *(const float4*)(hl + nl * HS + k4 * 4);
                float4 w0 = *(const float4*)(Wl + c * HS + k4 * 4);
                float4 w1 = *(const float4*)(Wl + (c + 16) * HS + k4 * 4);
                float4 w2 = *(const float4*)(Wl + (c + 32) * HS + k4 * 4);
                a0 = fmaf(hv.x, w0.x, a0); a0 = fmaf(hv.y, w0.y, a0);
                a0 = fmaf(hv.z, w0.z, a0); a0 = fmaf(hv.w, w0.w, a0);
                a1 = fmaf(hv.x, w1.x, a1); a1 = fmaf(hv.y, w1.y, a1);
                a1 = fmaf(hv.z, w1.z, a1); a1 = fmaf(hv.w, w1.w, a1);
                a2 = fmaf(hv.x, w2.x, a2); a2 = fmaf(hv.y, w2.y, a2);
                a2 = fmaf(hv.z, w2.z, a2); a2 = fmaf(hv.w, w2.w, a2);
            }
            float* op = out + (size_t)n * D;
            op[c]      = fmaxf(a0, 0.0f);
            op[c + 16] = fmaxf(a1, 0.0f);
            op[c + 32] = fmaxf(a2, 0.0f);
        }
    }
}

extern "C" void kernel_launch(void* const* d_in, const int* in_sizes, int n_in,
                              void* d_out, int out_size, void* d_ws, size_t ws_size,
                              hipStream_t stream) {
    const float* feat = (const float*)d_in[0];
    const int*   src  = (const int*)d_in[1];
    const int*   dst  = (const int*)d_in[2];
    const float* W    = (const float*)d_in[3];
    const float* b    = (const float*)d_in[4];
    float* out = (float*)d_out;

    char* ws = (char*)d_ws;
    unsigned int*   rec   = (unsigned int*)(ws + RECD_OFF);
    unsigned char*  srcb  = (unsigned char*)(ws + SRCB_OFF);
    float*          ci    = (float*)(ws + CI_OFF);
    unsigned short* offld = (unsigned short*)(ws + OFFLD_OFF);
    unsigned short* offls = (unsigned short*)(ws + OFFLS_OFF);

    k_prep<<<PB, 1024, 0, stream>>>(src, dst, rec, srcb, offld, offls);
    k_ci<<<NBIN_S, 512, 0, stream>>>(srcb, offls, ci);
    k_gcn<<<NBIN_D, 1024, 0, stream>>>(rec, offld, ci, feat, W, b, out);
}